// Round 4
// baseline (535.412 us; speedup 1.0000x reference)
//
#include <hip/hip_runtime.h>
#include <hip/hip_bf16.h>

typedef unsigned short ushort_t;
typedef short bf16x8 __attribute__((ext_vector_type(8)));
typedef float f32x4 __attribute__((ext_vector_type(4)));

#define LN2048_OVER_8 0.9530773732699248f  // ln(2048)/sqrt(64)
#define NEG_SENT (-1.0e30f)

__device__ inline float bf2f(ushort_t u) {
    unsigned int x = ((unsigned int)u) << 16;
    float f;
    __builtin_memcpy(&f, &x, 4);
    return f;
}

// round-to-nearest-even fp32 -> bf16 bits
__device__ inline ushort_t f2bf(float f) {
    unsigned int x;
    __builtin_memcpy(&x, &f, 4);
    unsigned int lsb = (x >> 16) & 1u;
    x += 0x7fffu + lsb;
    return (ushort_t)(x >> 16);
}

// load 8 contiguous fp32, convert to bf16x8 (RNE)
__device__ inline bf16x8 ld8f_bf(const float* __restrict__ p) {
    const float4 lo = *(const float4*)p;
    const float4 hi = *(const float4*)(p + 4);
    bf16x8 r;
    r[0] = (short)f2bf(lo.x); r[1] = (short)f2bf(lo.y);
    r[2] = (short)f2bf(lo.z); r[3] = (short)f2bf(lo.w);
    r[4] = (short)f2bf(hi.x); r[5] = (short)f2bf(hi.y);
    r[6] = (short)f2bf(hi.z); r[7] = (short)f2bf(hi.w);
    return r;
}

__device__ inline float rmax16(float v) {
    v = fmaxf(v, __shfl_xor(v, 1, 16));
    v = fmaxf(v, __shfl_xor(v, 2, 16));
    v = fmaxf(v, __shfl_xor(v, 4, 16));
    v = fmaxf(v, __shfl_xor(v, 8, 16));
    return v;
}
__device__ inline float rsum16(float v) {
    v += __shfl_xor(v, 1, 16);
    v += __shfl_xor(v, 2, 16);
    v += __shfl_xor(v, 4, 16);
    v += __shfl_xor(v, 8, 16);
    return v;
}

// ---------------------------------------------------------------------------
// Kernel 1: qkv = x @ w_qkv^T. X: [4096,1024] fp32, W: [3072,1024] fp32.
// Inline fp32->bf16 convert at fragment load; MFMA bf16; scatter bf16 q/k/v
// to [B,H,T,dh] workspaces. Per wave 64x64 tile; per block 128x128.
// ---------------------------------------------------------------------------
__global__ __launch_bounds__(256) void qkv_gemm(
    const float* __restrict__ X, const float* __restrict__ W,
    const float* __restrict__ qm,
    ushort_t* __restrict__ qws, ushort_t* __restrict__ kws, ushort_t* __restrict__ vws) {
    const int K = 1024;
    const int lane = threadIdx.x & 63;
    const int w = threadIdx.x >> 6;
    const int wi = w >> 1, wj = w & 1;
    const int m0 = blockIdx.y * 128 + wi * 64;
    const int n0 = blockIdx.x * 128 + wj * 64;
    const int l15 = lane & 15, quad = lane >> 4;

    f32x4 acc[4][4] = {};
    const float* Abase = X + (m0 + l15) * K + quad * 8;
    const float* Bbase = W + (n0 + l15) * K + quad * 8;

    for (int k = 0; k < K; k += 32) {
        bf16x8 a[4], b[4];
#pragma unroll
        for (int i = 0; i < 4; i++) {
            a[i] = ld8f_bf(Abase + i * 16 * K + k);
            b[i] = ld8f_bf(Bbase + i * 16 * K + k);
        }
#pragma unroll
        for (int i = 0; i < 4; i++)
#pragma unroll
            for (int j = 0; j < 4; j++)
                acc[i][j] = __builtin_amdgcn_mfma_f32_16x16x32_bf16(a[i], b[j], acc[i][j], 0, 0, 0);
    }

    // Epilogue: scatter. D layout: row = quad*4+r, col = l15 (m89/m91 verified).
#pragma unroll
    for (int j = 0; j < 4; j++) {
        const int n = n0 + j * 16 + l15;
        const int nl = n & 1023;          // column within the 1024-wide q/k/v slab
        const int h = nl >> 6, d = nl & 63;
        float qscale = 1.0f;
        if (n < 1024) qscale = LN2048_OVER_8 * qm[d];
#pragma unroll
        for (int i = 0; i < 4; i++) {
#pragma unroll
            for (int r = 0; r < 4; r++) {
                const int m = m0 + i * 16 + quad * 4 + r;
                const int bb = m >> 11;
                const int t = m & 2047;
                const long idx = (((long)(bb * 16 + h)) * 2048 + t) * 64 + d;
                float v = acc[i][j][r];
                if (n < 1024) {
                    qws[idx] = f2bf(v * qscale);
                } else if (n < 2048) {
                    kws[idx] = f2bf(v);
                } else {
                    vws[idx] = f2bf(v);
                }
            }
        }
    }
}

// ---------------------------------------------------------------------------
// Kernel 2: flash attention. Mask reduces to: key j valid iff j <= max(i,1023).
// One wave handles 16 queries of one (b,h); block = 4 waves = 64 queries.
// Block-uniform chunk count + __syncthreads around the LDS P-transpose.
// q/k/v: [BH=32, T=2048, dh=64] bf16. Output yws: [2,2048,1024] bf16.
// ---------------------------------------------------------------------------
__global__ __launch_bounds__(256) void attn(
    const ushort_t* __restrict__ qws, const ushort_t* __restrict__ kws,
    const ushort_t* __restrict__ vws, ushort_t* __restrict__ yws) {
    __shared__ ushort_t lds_p[4][16][32];   // per-wave P tile (16 q x 32 keys)

    const int lane = threadIdx.x & 63;
    const int w = threadIdx.x >> 6;
    const int l15 = lane & 15, quad = lane >> 4;
    const int bh = blockIdx.y;
    const int b = bh >> 4, h = bh & 15;
    const int q0 = blockIdx.x * 64 + w * 16;

    const ushort_t* qp = qws + (long)bh * 2048 * 64;
    const ushort_t* kp = kws + (long)bh * 2048 * 64;
    const ushort_t* vp = vws + (long)bh * 2048 * 64;

    // Q fragments (A-operand): lane holds Q[q0+l15][quad*8 + j (+32)]
    bf16x8 aq0 = *(const bf16x8*)(qp + (q0 + l15) * 64 + quad * 8);
    bf16x8 aq1 = *(const bf16x8*)(qp + (q0 + l15) * 64 + 32 + quad * 8);

    float m_run[4], l_run[4];
    f32x4 acc[4] = {};
#pragma unroll
    for (int r = 0; r < 4; r++) { m_run[r] = NEG_SENT; l_run[r] = 0.0f; }

    // Block-uniform trip count; per-wave wave-uniform `active` gates work so
    // every wave reaches every __syncthreads.
    const int q_hi = blockIdx.x * 64 + 63;
    const int kend_blk = ((q_hi > 1023) ? q_hi : 1023) + 1;
    const int nch = (kend_blk + 31) >> 5;
    const int my_kend = ((q0 + 15) > 1023 ? (q0 + 15) : 1023) + 1;
    const int bound_min = (q0 > 1023) ? q0 : 1023;

    for (int c = 0; c < nch; c++) {
        const int k0 = c * 32;
        const bool active = (k0 < my_kend);   // wave-uniform

        if (active) {
            // K fragments (B-operand): lane holds K[k0+kt*16+l15][quad*8+j (+32)]
            bf16x8 bk00 = *(const bf16x8*)(kp + (k0 + l15) * 64 + quad * 8);
            bf16x8 bk01 = *(const bf16x8*)(kp + (k0 + l15) * 64 + 32 + quad * 8);
            bf16x8 bk10 = *(const bf16x8*)(kp + (k0 + 16 + l15) * 64 + quad * 8);
            bf16x8 bk11 = *(const bf16x8*)(kp + (k0 + 16 + l15) * 64 + 32 + quad * 8);

            f32x4 s0 = {}, s1 = {};
            s0 = __builtin_amdgcn_mfma_f32_16x16x32_bf16(aq0, bk00, s0, 0, 0, 0);
            s0 = __builtin_amdgcn_mfma_f32_16x16x32_bf16(aq1, bk01, s0, 0, 0, 0);
            s1 = __builtin_amdgcn_mfma_f32_16x16x32_bf16(aq0, bk10, s1, 0, 0, 0);
            s1 = __builtin_amdgcn_mfma_f32_16x16x32_bf16(aq1, bk11, s1, 0, 0, 0);

            // validity per lane/row; explicit select to 0 for masked entries
            bool v0[4], v1[4];
#pragma unroll
            for (int r = 0; r < 4; r++) { v0[r] = true; v1[r] = true; }
            if (k0 + 31 > bound_min) {
#pragma unroll
                for (int r = 0; r < 4; r++) {
                    const int q = q0 + quad * 4 + r;
                    const int bnd = (q > 1023) ? q : 1023;
                    if (k0 + l15 > bnd)      { s0[r] = NEG_SENT; v0[r] = false; }
                    if (k0 + 16 + l15 > bnd) { s1[r] = NEG_SENT; v1[r] = false; }
                }
            }

            float alpha_arr[4];
#pragma unroll
            for (int r = 0; r < 4; r++) {
                const float mx = rmax16(fmaxf(s0[r], s1[r]));   // finite: >=1 valid key/row
                const float mnew = fmaxf(m_run[r], mx);
                const float alpha = (m_run[r] <= NEG_SENT) ? 0.0f : expf(m_run[r] - mnew);
                const float p0 = v0[r] ? expf(s0[r] - mnew) : 0.0f;
                const float p1 = v1[r] ? expf(s1[r] - mnew) : 0.0f;
                const ushort_t u0 = f2bf(p0);
                const ushort_t u1 = f2bf(p1);
                // self-consistent row sum: sum the bf16-rounded values fed to PV
                const float ps = rsum16(bf2f(u0) + bf2f(u1));
                l_run[r] = l_run[r] * alpha + ps;
                m_run[r] = mnew;
                alpha_arr[r] = alpha;
                lds_p[w][quad * 4 + r][l15] = u0;
                lds_p[w][quad * 4 + r][16 + l15] = u1;
            }
#pragma unroll
            for (int t = 0; t < 4; t++)
#pragma unroll
                for (int r = 0; r < 4; r++) acc[t][r] *= alpha_arr[r];
        }

        __syncthreads();   // P writes visible before reads

        if (active) {
            // A-operand layout read: P[q=l15][key=quad*8+j]
            const bf16x8 ap = *(const bf16x8*)(&lds_p[w][l15][quad * 8]);

            // PV: B-operand V[key=k0+quad*8+j][d=16t+l15]
            const ushort_t* vbase = vp + (long)(k0 + quad * 8) * 64 + l15;
#pragma unroll
            for (int t = 0; t < 4; t++) {
                bf16x8 bv;
#pragma unroll
                for (int j = 0; j < 8; j++) bv[j] = (short)vbase[j * 64 + t * 16];
                acc[t] = __builtin_amdgcn_mfma_f32_16x16x32_bf16(ap, bv, acc[t], 0, 0, 0);
            }
        }

        __syncthreads();   // reads done before next iteration's writes
    }

    // Store: y[b, t=q0+quad*4+r, h*64 + 16t + l15]  (D layout row=quad*4+r, col=l15)
#pragma unroll
    for (int t = 0; t < 4; t++) {
#pragma unroll
        for (int r = 0; r < 4; r++) {
            const int tq = q0 + quad * 4 + r;
            const float val = acc[t][r] / l_run[r];
            yws[((long)(b * 2048 + tq)) * 1024 + h * 64 + t * 16 + l15] = f2bf(val);
        }
    }
}

// ---------------------------------------------------------------------------
// Kernel 3: out = y @ w_proj^T. Y: [4096,1024] bf16 (ws), W: [1024,1024] fp32.
// Output: fp32 (reference output dtype).
// ---------------------------------------------------------------------------
__global__ __launch_bounds__(256) void proj_gemm(
    const ushort_t* __restrict__ Y, const float* __restrict__ W,
    float* __restrict__ Out) {
    const int K = 1024;
    const int lane = threadIdx.x & 63;
    const int w = threadIdx.x >> 6;
    const int wi = w >> 1, wj = w & 1;
    const int m0 = blockIdx.y * 128 + wi * 64;
    const int n0 = blockIdx.x * 128 + wj * 64;
    const int l15 = lane & 15, quad = lane >> 4;

    f32x4 acc[4][4] = {};
    const ushort_t* Abase = Y + (m0 + l15) * K + quad * 8;
    const float* Bbase = W + (n0 + l15) * K + quad * 8;

    for (int k = 0; k < K; k += 32) {
        bf16x8 a[4], b[4];
#pragma unroll
        for (int i = 0; i < 4; i++) {
            a[i] = *(const bf16x8*)(Abase + i * 16 * K + k);
            b[i] = ld8f_bf(Bbase + i * 16 * K + k);
        }
#pragma unroll
        for (int i = 0; i < 4; i++)
#pragma unroll
            for (int j = 0; j < 4; j++)
                acc[i][j] = __builtin_amdgcn_mfma_f32_16x16x32_bf16(a[i], b[j], acc[i][j], 0, 0, 0);
    }

#pragma unroll
    for (int i = 0; i < 4; i++) {
#pragma unroll
        for (int j = 0; j < 4; j++) {
#pragma unroll
            for (int r = 0; r < 4; r++) {
                const int m = m0 + i * 16 + quad * 4 + r;
                const int n = n0 + j * 16 + l15;
                Out[(long)m * 1024 + n] = acc[i][j][r];   // fp32 store
            }
        }
    }
}

extern "C" void kernel_launch(void* const* d_in, const int* in_sizes, int n_in,
                              void* d_out, int out_size, void* d_ws, size_t ws_size,
                              hipStream_t stream) {
    const float* x      = (const float*)d_in[0];  // [2,2048,1024] fp32
    const float* w_qkv  = (const float*)d_in[1];  // [3072,1024]   fp32
    const float* w_proj = (const float*)d_in[2];  // [1024,1024]   fp32
    const float* qm     = (const float*)d_in[3];  // [64]          fp32
    // d_in[4] = attn_mask: ignored — mask == (j <= max(i,1023)) computed inline.
    float* out = (float*)d_out;                   // [2,2048,1024] fp32

    const long HEADS_ELEMS = 2L * 16 * 2048 * 64;       // 4 Mi elements per tensor
    ushort_t* qws = (ushort_t*)d_ws;                    // 32 MiB ws total
    ushort_t* kws = qws + HEADS_ELEMS;
    ushort_t* vws = kws + HEADS_ELEMS;
    ushort_t* yws = vws + HEADS_ELEMS;                  // [2,2048,1024]

    qkv_gemm<<<dim3(24, 32), 256, 0, stream>>>(x, w_qkv, qm, qws, kws, vws);
    attn<<<dim3(32, 32), 256, 0, stream>>>(qws, kws, vws, yws);
    proj_gemm<<<dim3(8, 32), 256, 0, stream>>>(yws, w_proj, out);
}

// Round 5
// 466.824 us; speedup vs baseline: 1.1469x; 1.1469x over previous
//
#include <hip/hip_runtime.h>
#include <hip/hip_bf16.h>

typedef unsigned short ushort_t;
typedef short bf16x8 __attribute__((ext_vector_type(8)));
typedef float f32x4 __attribute__((ext_vector_type(4)));

// ln(2048)/sqrt(64) * log2(e) == log2(2048)/8 == 11/8 exactly
#define QSCALE_LOG2 1.375f
#define NEG_SENT (-1.0e30f)

__device__ inline float bf2f(ushort_t u) {
    unsigned int x = ((unsigned int)u) << 16;
    float f;
    __builtin_memcpy(&f, &x, 4);
    return f;
}

// round-to-nearest-even fp32 -> bf16 bits
__device__ inline ushort_t f2bf(float f) {
    unsigned int x;
    __builtin_memcpy(&x, &f, 4);
    unsigned int lsb = (x >> 16) & 1u;
    x += 0x7fffu + lsb;
    return (ushort_t)(x >> 16);
}

// load 8 contiguous fp32, convert to bf16x8 (RNE)
__device__ inline bf16x8 ld8f_bf(const float* __restrict__ p) {
    const float4 lo = *(const float4*)p;
    const float4 hi = *(const float4*)(p + 4);
    bf16x8 r;
    r[0] = (short)f2bf(lo.x); r[1] = (short)f2bf(lo.y);
    r[2] = (short)f2bf(lo.z); r[3] = (short)f2bf(lo.w);
    r[4] = (short)f2bf(hi.x); r[5] = (short)f2bf(hi.y);
    r[6] = (short)f2bf(hi.z); r[7] = (short)f2bf(hi.w);
    return r;
}

__device__ inline float rmax16(float v) {
    v = fmaxf(v, __shfl_xor(v, 1, 16));
    v = fmaxf(v, __shfl_xor(v, 2, 16));
    v = fmaxf(v, __shfl_xor(v, 4, 16));
    v = fmaxf(v, __shfl_xor(v, 8, 16));
    return v;
}
__device__ inline float rsum16(float v) {
    v += __shfl_xor(v, 1, 16);
    v += __shfl_xor(v, 2, 16);
    v += __shfl_xor(v, 4, 16);
    v += __shfl_xor(v, 8, 16);
    return v;
}

// ---------------------------------------------------------------------------
// Kernel 0: fp32 -> bf16 bulk convert (8 elems/thread). n % 2048 == 0.
// ---------------------------------------------------------------------------
__global__ __launch_bounds__(256) void cvt_bf16(
    const float* __restrict__ in, ushort_t* __restrict__ out) {
    const long i = ((long)blockIdx.x * 256 + threadIdx.x) * 8;
    *(bf16x8*)(out + i) = ld8f_bf(in + i);
}

// ---------------------------------------------------------------------------
// Kernel 1: qkv = xb @ wqkvb^T (pure bf16). XB: [4096,1024], WB: [3072,1024].
// Scatter q (scaled by 1.375*qm*log2-domain) / k to [BH,T,dh]; V TRANSPOSED
// to [BH,dh,T]. Per wave 64x64 tile; per block 128x128.
// ---------------------------------------------------------------------------
__global__ __launch_bounds__(256) void qkv_gemm(
    const ushort_t* __restrict__ XB, const ushort_t* __restrict__ WB,
    const float* __restrict__ qm,
    ushort_t* __restrict__ qws, ushort_t* __restrict__ kws, ushort_t* __restrict__ vtws) {
    const int K = 1024;
    const int lane = threadIdx.x & 63;
    const int w = threadIdx.x >> 6;
    const int wi = w >> 1, wj = w & 1;
    const int m0 = blockIdx.y * 128 + wi * 64;
    const int n0 = blockIdx.x * 128 + wj * 64;
    const int l15 = lane & 15, quad = lane >> 4;

    f32x4 acc[4][4] = {};
    const ushort_t* Abase = XB + (m0 + l15) * K + quad * 8;
    const ushort_t* Bbase = WB + (n0 + l15) * K + quad * 8;

    for (int k = 0; k < K; k += 32) {
        bf16x8 a[4], b[4];
#pragma unroll
        for (int i = 0; i < 4; i++) {
            a[i] = *(const bf16x8*)(Abase + i * 16 * K + k);
            b[i] = *(const bf16x8*)(Bbase + i * 16 * K + k);
        }
#pragma unroll
        for (int i = 0; i < 4; i++)
#pragma unroll
            for (int j = 0; j < 4; j++)
                acc[i][j] = __builtin_amdgcn_mfma_f32_16x16x32_bf16(a[i], b[j], acc[i][j], 0, 0, 0);
    }

    // Epilogue scatter. D layout: row = quad*4+r, col = l15 (m89/m91 verified).
#pragma unroll
    for (int j = 0; j < 4; j++) {
        const int n = n0 + j * 16 + l15;
        const int nl = n & 1023;
        const int h = nl >> 6, d = nl & 63;
        float qscale = 1.0f;
        if (n < 1024) qscale = QSCALE_LOG2 * qm[d];
#pragma unroll
        for (int i = 0; i < 4; i++) {
#pragma unroll
            for (int r = 0; r < 4; r++) {
                const int m = m0 + i * 16 + quad * 4 + r;
                const int bb = m >> 11;
                const int t = m & 2047;
                const float v = acc[i][j][r];
                if (n < 1024) {
                    qws[(((long)(bb * 16 + h)) * 2048 + t) * 64 + d] = f2bf(v * qscale);
                } else if (n < 2048) {
                    kws[(((long)(bb * 16 + h)) * 2048 + t) * 64 + d] = f2bf(v);
                } else {
                    vtws[(((long)(bb * 16 + h)) * 64 + d) * 2048 + t] = f2bf(v);
                }
            }
        }
    }
}

// ---------------------------------------------------------------------------
// Kernel 2: flash attention, 64-key chunks. Scores arrive in log2 domain
// (Q pre-scaled by log2e factor) -> exp2f softmax. Mask: key j valid iff
// j <= max(i,1023); masked scores = -1e30 -> exp2 underflows to exact 0.
// q/k: [BH,T,64] bf16; vt: [BH,64,T] bf16 (transposed). y: [2,2048,1024] bf16.
// ---------------------------------------------------------------------------
__global__ __launch_bounds__(256) void attn(
    const ushort_t* __restrict__ qws, const ushort_t* __restrict__ kws,
    const ushort_t* __restrict__ vtws, ushort_t* __restrict__ yws) {
    // P tile per wave: 16 q-rows x 64 keys, row padded to 72 ushorts (144 B =
    // 36 banks) so the b128 A-frag reads spread evenly over banks.
    __shared__ __attribute__((aligned(16))) ushort_t lds_p[4][16][72];

    const int lane = threadIdx.x & 63;
    const int w = threadIdx.x >> 6;
    const int l15 = lane & 15, quad = lane >> 4;
    const int bh = blockIdx.y;
    const int b = bh >> 4, h = bh & 15;
    const int q0 = blockIdx.x * 64 + w * 16;

    const ushort_t* qp = qws + (long)bh * 2048 * 64;
    const ushort_t* kp = kws + (long)bh * 2048 * 64;
    const ushort_t* vtp = vtws + (long)bh * 64 * 2048;

    // Q fragments (A-operand): lane holds Q[q0+l15][quad*8 + j (+32)]
    const bf16x8 aq0 = *(const bf16x8*)(qp + (q0 + l15) * 64 + quad * 8);
    const bf16x8 aq1 = *(const bf16x8*)(qp + (q0 + l15) * 64 + 32 + quad * 8);

    float m_run[4], l_run[4];
    f32x4 acc[4] = {};
#pragma unroll
    for (int r = 0; r < 4; r++) { m_run[r] = NEG_SENT; l_run[r] = 0.0f; }

    const int q_hi = blockIdx.x * 64 + 63;
    const int kend_blk = ((q_hi > 1023) ? q_hi : 1023) + 1;
    const int nch = (kend_blk + 63) >> 6;
    const int my_kend = ((q0 + 15) > 1023 ? (q0 + 15) : 1023) + 1;
    const int bound_min = (q0 > 1023) ? q0 : 1023;

    for (int c = 0; c < nch; c++) {
        const int k0 = c * 64;
        const bool active = (k0 < my_kend);   // wave-uniform

        if (active) {
            // QK^T over 4 key-16-tiles
            f32x4 s[4] = {};
#pragma unroll
            for (int kt = 0; kt < 4; kt++) {
                const ushort_t* kr = kp + (k0 + kt * 16 + l15) * 64 + quad * 8;
                const bf16x8 bk0 = *(const bf16x8*)kr;
                const bf16x8 bk1 = *(const bf16x8*)(kr + 32);
                s[kt] = __builtin_amdgcn_mfma_f32_16x16x32_bf16(aq0, bk0, s[kt], 0, 0, 0);
                s[kt] = __builtin_amdgcn_mfma_f32_16x16x32_bf16(aq1, bk1, s[kt], 0, 0, 0);
            }

            if (k0 + 63 > bound_min) {   // boundary: causal/memory mask
#pragma unroll
                for (int kt = 0; kt < 4; kt++) {
                    const int key = k0 + kt * 16 + l15;
#pragma unroll
                    for (int r = 0; r < 4; r++) {
                        const int qrow = q0 + quad * 4 + r;
                        const int bnd = (qrow > 1023) ? qrow : 1023;
                        if (key > bnd) s[kt][r] = NEG_SENT;
                    }
                }
            }

            float alpha_arr[4];
#pragma unroll
            for (int r = 0; r < 4; r++) {
                const float m4 = fmaxf(fmaxf(s[0][r], s[1][r]), fmaxf(s[2][r], s[3][r]));
                const float mx = rmax16(m4);                 // finite: >=1 valid key/row
                const float mnew = fmaxf(m_run[r], mx);
                const float alpha = exp2f(m_run[r] - mnew);  // first chunk: exp2(-1e30)=0
                float psum = 0.0f;
#pragma unroll
                for (int kt = 0; kt < 4; kt++) {
                    const float p = exp2f(s[kt][r] - mnew);  // masked -> exact 0
                    const ushort_t u = f2bf(p);
                    lds_p[w][quad * 4 + r][kt * 16 + l15] = u;
                    psum += bf2f(u);                          // sum what PV will see
                }
                l_run[r] = l_run[r] * alpha + rsum16(psum);
                m_run[r] = mnew;
                alpha_arr[r] = alpha;
            }
#pragma unroll
            for (int t = 0; t < 4; t++)
#pragma unroll
                for (int r = 0; r < 4; r++) acc[t][r] *= alpha_arr[r];
        }

        __syncthreads();   // P writes visible before reads

        if (active) {
            // A-operand reads: P[q=l15][key=quad*8+j] and [32+quad*8+j]
            const bf16x8 ap0 = *(const bf16x8*)(&lds_p[w][l15][quad * 8]);
            const bf16x8 ap1 = *(const bf16x8*)(&lds_p[w][l15][32 + quad * 8]);

            // PV: B-operand V[key][d] from transposed vt[d][key] -> vector loads
#pragma unroll
            for (int t = 0; t < 4; t++) {
                const ushort_t* vb = vtp + (long)(t * 16 + l15) * 2048 + k0 + quad * 8;
                const bf16x8 bv0 = *(const bf16x8*)vb;
                const bf16x8 bv1 = *(const bf16x8*)(vb + 32);
                acc[t] = __builtin_amdgcn_mfma_f32_16x16x32_bf16(ap0, bv0, acc[t], 0, 0, 0);
                acc[t] = __builtin_amdgcn_mfma_f32_16x16x32_bf16(ap1, bv1, acc[t], 0, 0, 0);
            }
        }

        __syncthreads();   // reads done before next iteration's writes
    }

    // Store: y[b, t=q0+quad*4+r, h*64 + 16t + l15]
#pragma unroll
    for (int t = 0; t < 4; t++) {
#pragma unroll
        for (int r = 0; r < 4; r++) {
            const int tq = q0 + quad * 4 + r;
            const float val = acc[t][r] / l_run[r];
            yws[((long)(b * 2048 + tq)) * 1024 + h * 64 + t * 16 + l15] = f2bf(val);
        }
    }
}

// ---------------------------------------------------------------------------
// Kernel 3: out = y @ w_proj^T. Y: [4096,1024] bf16 (ws), W: [1024,1024] fp32
// (inline cvt, only 8 re-reads). Output fp32.
// ---------------------------------------------------------------------------
__global__ __launch_bounds__(256) void proj_gemm(
    const ushort_t* __restrict__ Y, const float* __restrict__ W,
    float* __restrict__ Out) {
    const int K = 1024;
    const int lane = threadIdx.x & 63;
    const int w = threadIdx.x >> 6;
    const int wi = w >> 1, wj = w & 1;
    const int m0 = blockIdx.y * 128 + wi * 64;
    const int n0 = blockIdx.x * 128 + wj * 64;
    const int l15 = lane & 15, quad = lane >> 4;

    f32x4 acc[4][4] = {};
    const ushort_t* Abase = Y + (m0 + l15) * K + quad * 8;
    const float* Bbase = W + (n0 + l15) * K + quad * 8;

    for (int k = 0; k < K; k += 32) {
        bf16x8 a[4], b[4];
#pragma unroll
        for (int i = 0; i < 4; i++) {
            a[i] = *(const bf16x8*)(Abase + i * 16 * K + k);
            b[i] = ld8f_bf(Bbase + i * 16 * K + k);
        }
#pragma unroll
        for (int i = 0; i < 4; i++)
#pragma unroll
            for (int j = 0; j < 4; j++)
                acc[i][j] = __builtin_amdgcn_mfma_f32_16x16x32_bf16(a[i], b[j], acc[i][j], 0, 0, 0);
    }

#pragma unroll
    for (int i = 0; i < 4; i++) {
#pragma unroll
        for (int j = 0; j < 4; j++) {
#pragma unroll
            for (int r = 0; r < 4; r++) {
                const int m = m0 + i * 16 + quad * 4 + r;
                const int n = n0 + j * 16 + l15;
                Out[(long)m * 1024 + n] = acc[i][j][r];
            }
        }
    }
}

extern "C" void kernel_launch(void* const* d_in, const int* in_sizes, int n_in,
                              void* d_out, int out_size, void* d_ws, size_t ws_size,
                              hipStream_t stream) {
    const float* x      = (const float*)d_in[0];  // [2,2048,1024] fp32
    const float* w_qkv  = (const float*)d_in[1];  // [3072,1024]   fp32
    const float* w_proj = (const float*)d_in[2];  // [1024,1024]   fp32
    const float* qm     = (const float*)d_in[3];  // [64]          fp32
    // d_in[4] = attn_mask: ignored — mask == (j <= max(i,1023)) computed inline.
    float* out = (float*)d_out;                   // [2,2048,1024] fp32

    // Workspace layout (38 MiB):
    //   [0,6M):   wqkvb  bf16 w_qkv           (3M elems)
    //   [6,14M):  qws    bf16 [32,2048,64]
    //   [14,22M): kws    bf16 [32,2048,64]
    //   [22,30M): vtws   bf16 [32,64,2048]  (V transposed)
    //   [30,38M): xb     bf16 x  -> reused as yws after qkv_gemm consumes it
    ushort_t* wqkvb = (ushort_t*)d_ws;
    ushort_t* qws   = wqkvb + 3L * 1024 * 1024;
    ushort_t* kws   = qws   + 4L * 1024 * 1024;
    ushort_t* vtws  = kws   + 4L * 1024 * 1024;
    ushort_t* xb    = vtws  + 4L * 1024 * 1024;
    ushort_t* yws   = xb;   // alias: x-tile dead after qkv_gemm

    cvt_bf16<<<2048, 256, 0, stream>>>(x, xb);          // 4M elems
    cvt_bf16<<<1536, 256, 0, stream>>>(w_qkv, wqkvb);   // 3M elems
    qkv_gemm<<<dim3(24, 32), 256, 0, stream>>>(xb, wqkvb, qm, qws, kws, vtws);
    attn<<<dim3(32, 32), 256, 0, stream>>>(qws, kws, vtws, yws);
    proj_gemm<<<dim3(8, 32), 256, 0, stream>>>(yws, w_proj, out);
}